// Round 1
// 12481.757 us; speedup vs baseline: 1.3583x; 1.3583x over previous
//
#include <hip/hip_runtime.h>
#include <cstdint>

// ============================================================================
// EncoderLSTMReal: reverse LSTM (T=200,B=1024,H=512,IN=64) + 2 tanh-MLP heads.
// CONTRACT (established R0-R8):
//   - inputs fp32, dict order (R6 NaN kills bf16-input; R5 permutation test)
//   - OUTPUT FLOAT32 (R8 probe: a bf16-stride write at out[0] was invisible
//     to the readout => 4-byte elements; mu = out[0..32768), logvar next)
//   - engines R4(tiled) == R7(naive) function-identical (same 0.574 signature)
// Round-10: R9 pipeline + LDS-staged weights in lstm_step.
//   Theory: inner loop streamed wv[8] from L2 per-thread (2.4 GB/step, 16x
//   redundant within a block) => L2-BW-bound at ~70 of 95 us. Stage the
//   128x64 per-chunk W slice (32 KB) in LDS once per block instead.
//   LDS: sAT 9.2K + sW 34.8K + sG 16.9K = 60.9 KB < 64 KB, 2 blocks/CU kept.
// ws: [0,256) maxm; [256,+2MB) c; [+2MB,+6MB) h[2][1024][512] f32;
//     [+6MB,...) z f32 [2][1024][520]. Total ~10.5 MB.
// ============================================================================

typedef unsigned short U16;
typedef __attribute__((ext_vector_type(4))) float f32x4;
typedef __attribute__((ext_vector_type(2))) float f32x2;

#define DEV __device__ __forceinline__

DEV float sigf(float x) { return 1.0f / (1.0f + expf(-x)); }

// ============================ per-step LSTM =================================
// grid 512 = 32 mtile x 16 ntile; block 256.
__global__ void __launch_bounds__(256, 2)
lstm_step_valu(const float* __restrict__ x, const float* __restrict__ a,
               const float* __restrict__ w_ih, const float* __restrict__ w_hh,
               const float* __restrict__ b_ih, const float* __restrict__ b_hh,
               const float* __restrict__ h_in, float* __restrict__ h_out,
               float* __restrict__ c_ws, const float* __restrict__ maxm_p,
               int s) {
  __shared__ float sAT[64 * 36];        // [k][row]: 64 k x 32 rows, pad 36
  __shared__ float sW[128 * 68];        // [l][k]: 128 local cols x 64 k, pad 68
  __shared__ float sG[4][32 * 33];      // i,f,g,o gates, padded

  const int tid = threadIdx.x;
  const int rg = tid & 15;              // rows rg*2, rg*2+1
  const int cgrp = tid >> 4;            // local cols cgrp*8..+7 (of 128)
  const int bid = blockIdx.x;
  const int ntile = bid & 15, mtile = bid >> 4;
  const int m0 = mtile * 32, j0 = ntile * 32;
  const int gate = cgrp >> 2;           // local col l = cgrp*8+c:
  const int jjb = (cgrp & 3) * 8;       //   gate = l>>5, jj = (l&31)
  const int ngbase = gate * 512 + j0 + jjb;   // w row of col c: ngbase + c

  float acc0[8], acc1[8];
#pragma unroll
  for (int c = 0; c < 8; c++) { acc0[c] = 0.f; acc1[c] = 0.f; }

  const float ts = (float)s / (*maxm_p);
  const int nch = (s == 0) ? 1 : 9;     // h == 0 at s == 0

  for (int ch = 0; ch < nch; ch++) {
    // ---- stage A chunk transposed: sAT[k][row] ----
    if (ch == 0) {                      // x_in: 0..47 x, 48..62 a, 63 t
      size_t srow = (size_t)(199 - s) * 1024 + (size_t)m0;
      for (int idx = tid; idx < 2048; idx += 256) {
        int row = idx >> 6, k = idx & 63;
        float v;
        if (k < 48)      v = x[(srow + row) * 48 + k];
        else if (k < 63) v = a[(srow + row) * 15 + (k - 48)];
        else             v = ts;        // exact fp32, same as reference
        sAT[k * 36 + row] = v;
      }
    } else {
      int k0 = (ch - 1) * 64;
      for (int idx = tid; idx < 2048; idx += 256) {
        int row = idx >> 6, k = idx & 63;
        sAT[k * 36 + row] = h_in[(size_t)(m0 + row) * 512 + k0 + k];
      }
    }

    // ---- stage W chunk: sW[l][k], l = local col 0..127, k local 0..63 ----
    // local col l -> weight row (l>>5)*512 + j0 + (l&31); matches compute's
    // l = cgrp*8+c => row ngbase+c (verified: l>>5==cgrp>>2, l&31==jjb+c).
    {
      const float* wsrc; int wstr, koff;
      if (ch == 0) { wsrc = w_ih; wstr = 64;  koff = 0; }
      else         { wsrc = w_hh; wstr = 512; koff = (ch - 1) * 64; }
#pragma unroll
      for (int it = 0; it < 8; it++) {
        int l = cgrp + it * 16;         // 8 iters x 16 rows = 128 rows
        int wrow = (l >> 5) * 512 + j0 + (l & 31);
        f32x4 v = *(const f32x4*)(wsrc + (size_t)wrow * wstr + koff + rg * 4);
        *(f32x4*)&sW[l * 68 + rg * 4] = v;
      }
    }
    __syncthreads();

#pragma unroll 4
    for (int k4 = 0; k4 < 16; k4++) {
      f32x4 wv[8];
#pragma unroll
      for (int c = 0; c < 8; c++)
        wv[c] = *(const f32x4*)&sW[(cgrp * 8 + c) * 68 + k4 * 4];
      f32x2 rv[4];
#pragma unroll
      for (int kk = 0; kk < 4; kk++)
        rv[kk] = *(const f32x2*)&sAT[(k4 * 4 + kk) * 36 + rg * 2];
#pragma unroll
      for (int kk = 0; kk < 4; kk++)
#pragma unroll
        for (int c = 0; c < 8; c++) {
          acc0[c] += rv[kk][0] * wv[c][kk];
          acc1[c] += rv[kk][1] * wv[c][kk];
        }
    }
    __syncthreads();
  }

  // ---- gates (+bias) -> LDS ----
#pragma unroll
  for (int c = 0; c < 8; c++) {
    int ng = ngbase + c;
    float bias = b_ih[ng] + b_hh[ng];
    sG[gate][(rg * 2 + 0) * 33 + jjb + c] = acc0[c] + bias;
    sG[gate][(rg * 2 + 1) * 33 + jjb + c] = acc1[c] + bias;
  }
  __syncthreads();

  // ---- elementwise cell: 4 elems/thread; c,h fp32 in ws ----
  {
    int m = tid >> 3, jq = (tid & 7) * 4;
    size_t base = (size_t)(m0 + m) * 512 + j0 + jq;
    f32x4 cv = {0.f, 0.f, 0.f, 0.f};
    if (s > 0) cv = *(const f32x4*)&c_ws[base];
    f32x4 ncv, hv;
#pragma unroll
    for (int u = 0; u < 4; u++) {
      int jj = jq + u;
      float gi = sG[0][m * 33 + jj];
      float gf = sG[1][m * 33 + jj];
      float gg = sG[2][m * 33 + jj];
      float go = sG[3][m * 33 + jj];
      float c = sigf(gf) * cv[u] + sigf(gi) * tanhf(gg);
      ncv[u] = c;
      hv[u] = sigf(go) * tanhf(c);
    }
    *(f32x4*)&c_ws[base] = ncv;
    *(f32x4*)&h_out[base] = hv;
  }
}

// ============================= max(m) =======================================
__global__ void __launch_bounds__(1024)
maxm_kernel(const float* __restrict__ mv, float* __restrict__ out) {
  __shared__ float red[1024];
  int tid = threadIdx.x;
  float mx = -3.0e38f;
  for (int i = tid; i < 200 * 1024; i += 1024) mx = fmaxf(mx, mv[i]);
  red[tid] = mx;
  __syncthreads();
  for (int s = 512; s > 0; s >>= 1) {
    if (tid < s) red[tid] = fmaxf(red[tid], red[tid + s]);
    __syncthreads();
  }
  if (tid == 0) *out = red[0];
}

// ============ head layer 1: z = tanh(h @ {lw1,vw1}^T + b1) ==================
__global__ void __launch_bounds__(256, 2)
head1_valu(const float* __restrict__ h, const float* __restrict__ lw1,
           const float* __restrict__ lb1, const float* __restrict__ vw1,
           const float* __restrict__ vb1, float* __restrict__ z) {
  __shared__ float sAT[64 * 68];        // [k][row]: 64 k x 64 rows, pad 68
  const int tid = threadIdx.x;
  const int rg = tid & 15;              // rows rg*4..+3
  const int cgrp = tid >> 4;            // cols n0+cgrp*4..+3
  const int bid = blockIdx.x;
  const int mt = bid & 15, nt = bid >> 4;
  const int m0 = mt * 64;
  const int nb = nt * 64 + cgrp * 4;

  const float* wr[4];
  float bias[4];
  int hdv[4], wnv[4], valid[4];
#pragma unroll
  for (int c = 0; c < 4; c++) {
    int n = nb + c;
    valid[c] = (n < 1026);
    int hd = valid[c] ? (n >= 513) : 0;
    int wn = valid[c] ? (n - hd * 513) : 0;
    hdv[c] = hd; wnv[c] = wn;
    wr[c] = (hd ? vw1 : lw1) + (size_t)wn * 512;
    bias[c] = valid[c] ? (hd ? vb1[wn] : lb1[wn]) : 0.f;
  }

  float acc[4][4];
#pragma unroll
  for (int i = 0; i < 4; i++)
#pragma unroll
    for (int c = 0; c < 4; c++) acc[i][c] = 0.f;

  for (int ch = 0; ch < 8; ch++) {
    int k0 = ch * 64;
    for (int idx = tid; idx < 4096; idx += 256) {
      int row = idx >> 6, k = idx & 63;
      sAT[k * 68 + row] = h[(size_t)(m0 + row) * 512 + k0 + k];
    }
    __syncthreads();
#pragma unroll 4
    for (int k4 = 0; k4 < 16; k4++) {
      f32x4 wv[4];
#pragma unroll
      for (int c = 0; c < 4; c++)
        wv[c] = *(const f32x4*)(wr[c] + k0 + k4 * 4);
      f32x4 rv[4];
#pragma unroll
      for (int kk = 0; kk < 4; kk++)
        rv[kk] = *(const f32x4*)&sAT[(k4 * 4 + kk) * 68 + rg * 4];
#pragma unroll
      for (int kk = 0; kk < 4; kk++)
#pragma unroll
        for (int c = 0; c < 4; c++) {
          acc[0][c] += rv[kk][0] * wv[c][kk];
          acc[1][c] += rv[kk][1] * wv[c][kk];
          acc[2][c] += rv[kk][2] * wv[c][kk];
          acc[3][c] += rv[kk][3] * wv[c][kk];
        }
    }
    __syncthreads();
  }
#pragma unroll
  for (int c = 0; c < 4; c++) {
    if (!valid[c]) continue;
#pragma unroll
    for (int i = 0; i < 4; i++) {
      int m = m0 + rg * 4 + i;
      z[(size_t)hdv[c] * 1024 * 520 + (size_t)m * 520 + wnv[c]] =
          tanhf(acc[i][c] + bias[c]);
    }
  }
}

// ============ head layer 2: out = tanh(z @ {lw2,vw2}^T + b2) ================
// OUTPUT IS FLOAT32: out[hd*32768 + m*32 + n].
__global__ void __launch_bounds__(256)
head2_valu(const float* __restrict__ z, const float* __restrict__ lw2,
           const float* __restrict__ lb2, const float* __restrict__ vw2,
           const float* __restrict__ vb2, float* __restrict__ out) {
  __shared__ float sZ[8 * 133];
  __shared__ float sW[32 * 133];
  const int tid = threadIdx.x;
  const int bid = blockIdx.x;           // 0..255
  const int gr0 = bid * 8;              // rows of the 2048 concat rows
  const int hd = gr0 >> 10;
  const int b0 = gr0 & 1023;
  const float* w2 = hd ? vw2 : lw2;
  const float* b2 = hd ? vb2 : lb2;
  const float* zh = z + (size_t)hd * 1024 * 520;
  const int rloc = tid >> 5, col = tid & 31;
  float acc = 0.f;

  for (int ch = 0; ch < 5; ch++) {
    int kc = ch * 128;
    for (int idx = tid; idx < 1024; idx += 256) {
      int row = idx >> 7, k = idx & 127;
      int kk = kc + k;
      sZ[row * 133 + k] = (kk < 513) ? zh[(size_t)(b0 + row) * 520 + kk] : 0.f;
    }
    for (int idx = tid; idx < 4096; idx += 256) {
      int row = idx >> 7, k = idx & 127;
      int kk = kc + k;
      sW[row * 133 + k] = (kk < 513) ? w2[(size_t)row * 513 + kk] : 0.f;
    }
    __syncthreads();
#pragma unroll 8
    for (int k = 0; k < 128; k++)
      acc += sZ[rloc * 133 + k] * sW[col * 133 + k];
    __syncthreads();
  }
  out[(size_t)hd * 32768 + (size_t)(b0 + rloc) * 32 + col] = tanhf(acc + b2[col]);
}

// ============================================================================
extern "C" void kernel_launch(void* const* d_in, const int* in_sizes, int n_in,
                              void* d_out, int out_size, void* d_ws, size_t ws_size,
                              hipStream_t stream) {
  (void)in_sizes; (void)n_in; (void)out_size; (void)ws_size;
  const float* x    = (const float*)d_in[0];
  const float* a    = (const float*)d_in[1];
  const float* mm   = (const float*)d_in[2];
  const float* w_ih = (const float*)d_in[3];
  const float* w_hh = (const float*)d_in[4];
  const float* b_ih = (const float*)d_in[5];
  const float* b_hh = (const float*)d_in[6];
  const float* lw1  = (const float*)d_in[7];
  const float* lb1  = (const float*)d_in[8];
  const float* lw2  = (const float*)d_in[9];
  const float* lb2  = (const float*)d_in[10];
  const float* vw1  = (const float*)d_in[11];
  const float* vb1  = (const float*)d_in[12];
  const float* vw2  = (const float*)d_in[13];
  const float* vb2  = (const float*)d_in[14];

  char* wsb = (char*)d_ws;
  float* maxm = (float*)wsb;                                   // 256 B
  float* c_ws = (float*)(wsb + 256);                           // 2 MB
  float* hbuf = (float*)(wsb + 256 + 1024 * 512 * 4);          // 2 x 2 MB
  float* z    = (float*)(wsb + 256 + 3 * 1024 * 512 * 4);      // 2x1024x520 f32

  maxm_kernel<<<1, 1024, 0, stream>>>(mm, maxm);
  for (int s = 0; s < 200; s++) {
    const float* h_in = hbuf + (size_t)(s & 1) * 1024 * 512;
    float* h_out = hbuf + (size_t)((s & 1) ^ 1) * 1024 * 512;
    lstm_step_valu<<<512, 256, 0, stream>>>(x, a, w_ih, w_hh, b_ih, b_hh,
                                            h_in, h_out, c_ws, maxm, s);
  }
  // s=199 wrote hbuf[0]
  head1_valu<<<272, 256, 0, stream>>>(hbuf, lw1, lb1, vw1, vb1, z);
  head2_valu<<<256, 256, 0, stream>>>(z, lw2, lb2, vw2, vb2, (float*)d_out);
}